// Round 7
// baseline (955.831 us; speedup 1.0000x reference)
//
#include <hip/hip_runtime.h>
#include <hip/hip_bf16.h>

// ---------------------------------------------------------------------------
// GIN0 (GINE x3 + BN + head) forward.
// R1: CSR + per-node register aggregation (no atomics in hot path).
// R3: node MLP GEMMs on MFMA via split-bf16 (hi+lo, 3-pass).
// R5: BN stats fused into GEMM2 epilogue; single prep kernel.
// R6: gathers read a bf16 copy of h; self-term fp32.
// R8: WPN waves/node so We slice stays VGPR-resident.
// R15: eacsr (ea in CSR order) + one-base immediate-offset ea loads.
// R16: packed FMA WITHOUT inline asm. R15's "v"(u64) asm operands forced
//      ~2 v_mov per pkfma (reg-pair coalescing failure; 83 VALU/edge
//      measured vs ~27 source). Replace with compiler-native form:
//      __builtin_shufflevector splat of a float2v element feeds
//      __builtin_elementwise_fma -> ISel emits v_pk_fma_f32 with op_sel
//      broadcast, zero movs, full scheduling freedom. Same fp32 math.
// ---------------------------------------------------------------------------

typedef __attribute__((ext_vector_type(8))) short short8;
typedef __attribute__((ext_vector_type(4))) float floatx4;
typedef __attribute__((ext_vector_type(2))) float float2v;

__device__ __forceinline__ float2v bcast_lo(float2v e) {
    return __builtin_shufflevector(e, e, 0, 0);
}
__device__ __forceinline__ float2v bcast_hi(float2v e) {
    return __builtin_shufflevector(e, e, 1, 1);
}

__device__ __forceinline__ ushort f2bf_rne(float x) {
    unsigned u = __float_as_uint(x);
    unsigned r = (u + 0x7FFFu + ((u >> 16) & 1u)) >> 16;
    return (ushort)r;
}

__device__ __forceinline__ float bf2f(ushort u) {
    return __uint_as_float(((unsigned)u) << 16);
}

// ---------------- CSR build ----------------

__global__ __launch_bounds__(256) void hist_kernel(const int* __restrict__ dst,
                                                   int* __restrict__ deg, int E) {
    int i = blockIdx.x * blockDim.x + threadIdx.x;
    int stride = gridDim.x * blockDim.x;
    for (; i < E; i += stride) atomicAdd(&deg[dst[i]], 1);
}

__global__ __launch_bounds__(1024) void scan_kernel(const int* __restrict__ deg,
                                                    int* __restrict__ row_start, int N) {
    __shared__ int part[1024];
    int tid = threadIdx.x;
    int per = (N + 1023) / 1024;
    int start = tid * per;
    int end = min(start + per, N);
    int s = 0;
    for (int i = start; i < end; ++i) s += deg[i];
    part[tid] = s;
    __syncthreads();
    // Hillis-Steele inclusive scan over the 1024 partials
    for (int off = 1; off < 1024; off <<= 1) {
        int t = (tid >= off) ? part[tid - off] : 0;
        __syncthreads();
        part[tid] += t;
        __syncthreads();
    }
    int run = part[tid] - s;  // exclusive prefix
    for (int i = start; i < end; ++i) {
        row_start[i] = run;
        run += deg[i];
    }
    if (tid == 1023) row_start[N] = part[1023];
}

__global__ __launch_bounds__(256) void scatter_kernel(
    const int* __restrict__ src, const int* __restrict__ dst,
    const int* __restrict__ row_start, int* __restrict__ cursor,
    int* __restrict__ ceid, int* __restrict__ csrc, int E) {
    int i = blockIdx.x * blockDim.x + threadIdx.x;
    int stride = gridDim.x * blockDim.x;
    for (; i < E; i += stride) {
        int v = dst[i];
        int p = row_start[v] + atomicAdd(&cursor[v], 1);
        ceid[p] = i;
        csrc[p] = src[i];
    }
}

// ---------------- ea -> CSR order (fp32 stream for the agg loop) ----------
__global__ __launch_bounds__(256) void eacsr_gather(const float* __restrict__ ea,
                                                    const int* __restrict__ ceid,
                                                    float* __restrict__ eacsr, long total) {
    long t = (long)blockIdx.x * 256 + threadIdx.x;
    long stride = (long)gridDim.x * 256;
    for (; t < total; t += stride) {
        long p = t >> 4;
        int c = (int)(t & 15);
        eacsr[t] = ea[(size_t)ceid[p] * 16 + c];
    }
}

// ---------------- Weight prep (node MLP GEMM weights) ----------------
__device__ __forceinline__ void wsplit(const float* W, ushort* Wth, ushort* Wtl,
                                       int K, int N, int t) {
    int k = t / N, n = t - k * N;
    float v = W[t];
    ushort hv = f2bf_rne(v);
    float hf = bf2f(hv);
    ushort lv = f2bf_rne(v - hf);
    Wth[(size_t)n * K + k] = hv;
    Wtl[(size_t)n * K + k] = lv;
}

__global__ __launch_bounds__(256) void prep_all(
    const float* W11, ushort* W11h, ushort* W11l,
    const float* W12, ushort* W12h, ushort* W12l,
    const float* W21, ushort* W21h, ushort* W21l,
    const float* W22, ushort* W22h, ushort* W22l,
    const float* W31, ushort* W31h, ushort* W31l,
    const float* W32, ushort* W32h, ushort* W32l) {
    int t = blockIdx.x * blockDim.x + threadIdx.x;
    const int s1 = 128 * 256, s2 = s1 + 256 * 256, s3 = s2 + 256 * 128;
    const int s4 = s3 + 128 * 128, s5 = s4 + 128 * 64, s6 = s5 + 64 * 64;
    if (t < s1) wsplit(W11, W11h, W11l, 128, 256, t);
    else if (t < s2) wsplit(W12, W12h, W12l, 256, 256, t - s1);
    else if (t < s3) wsplit(W21, W21h, W21l, 256, 128, t - s2);
    else if (t < s4) wsplit(W22, W22h, W22l, 128, 128, t - s3);
    else if (t < s5) wsplit(W31, W31h, W31l, 128, 64, t - s4);
    else if (t < s6) wsplit(W32, W32h, W32l, 64, 64, t - s5);
}

// ---------------- fp32 -> bf16 convert (layer-1 gather copy) --------------
__global__ __launch_bounds__(256) void f32_to_bf16(const float* __restrict__ in,
                                                   ushort* __restrict__ out, long n4) {
    long i = (long)blockIdx.x * blockDim.x + threadIdx.x;
    long stride = (long)gridDim.x * blockDim.x;
    for (; i < n4; i += stride) {
        float4 v = ((const float4*)in)[i];
        ushort4 o;
        o.x = f2bf_rne(v.x);
        o.y = f2bf_rne(v.y);
        o.z = f2bf_rne(v.z);
        o.w = f2bf_rne(v.w);
        ((ushort4*)out)[i] = o;
    }
}

// ---------------- Fused GINE aggregation ----------------
// Per edge: acc += relu(proj(ea) + x_src). ea read sequentially from eacsr
// as float2v pairs; shufflevector splats -> v_pk_fma_f32 op_sel broadcast
// (compiler-selected, no asm, no movs). 4-edge blocks: one per-lane csrc
// dword + 4 readlanes -> 4 batched row gathers issued before the FMAs.
template <int D, int WPN>
__global__ __launch_bounds__(256) void gine_agg_kernel(
    const float* __restrict__ h, const ushort* __restrict__ hb,
    const float* __restrict__ eacsr,
    const int* __restrict__ row_start, const int* __restrict__ csrc,
    const float* __restrict__ We, const float* __restrict__ be,
    ushort* __restrict__ uhi, ushort* __restrict__ ulo, int N) {
    constexpr int NPB = 4 / WPN;  // nodes per 256-thread block
    const int lane = threadIdx.x & 63;
    const int wid = threadIdx.x >> 6;
    const int ch0 = (wid % WPN) * 128 + lane * 2;

    float2v w[16];
#pragma unroll
    for (int k = 0; k < 16; ++k) w[k] = *(const float2v*)&We[k * D + ch0];
    const float2v bias = *(const float2v*)&be[ch0];

    const int v = blockIdx.x * NPB + wid / WPN;
    if (v >= N) return;
    float2v z2; z2[0] = 0.f; z2[1] = 0.f;
    float2v acc = z2;

    int i = __builtin_amdgcn_readfirstlane(row_start[v]);
    const int e1 = __builtin_amdgcn_readfirstlane(row_start[v + 1]);

    // COMPE: one edge = 8 float2v (16 ea dims); splat->pk_fma per dim.
#define COMPE(EP, r)                                                  \
    {                                                                 \
        const float2v* ep_ = (EP);                                    \
        float2v p = bias;                                             \
        float2v e0 = ep_[0], e1v = ep_[1], e2 = ep_[2], e3 = ep_[3];  \
        float2v e4 = ep_[4], e5 = ep_[5], e6 = ep_[6], e7 = ep_[7];   \
        p = __builtin_elementwise_fma(bcast_lo(e0), w[0], p);         \
        p = __builtin_elementwise_fma(bcast_hi(e0), w[1], p);         \
        p = __builtin_elementwise_fma(bcast_lo(e1v), w[2], p);        \
        p = __builtin_elementwise_fma(bcast_hi(e1v), w[3], p);        \
        p = __builtin_elementwise_fma(bcast_lo(e2), w[4], p);         \
        p = __builtin_elementwise_fma(bcast_hi(e2), w[5], p);         \
        p = __builtin_elementwise_fma(bcast_lo(e3), w[6], p);         \
        p = __builtin_elementwise_fma(bcast_hi(e3), w[7], p);         \
        p = __builtin_elementwise_fma(bcast_lo(e4), w[8], p);         \
        p = __builtin_elementwise_fma(bcast_hi(e4), w[9], p);         \
        p = __builtin_elementwise_fma(bcast_lo(e5), w[10], p);        \
        p = __builtin_elementwise_fma(bcast_hi(e5), w[11], p);        \
        p = __builtin_elementwise_fma(bcast_lo(e6), w[12], p);        \
        p = __builtin_elementwise_fma(bcast_hi(e6), w[13], p);        \
        float2v hv;                                                   \
        hv[0] = __uint_as_float((r) << 16);                           \
        hv[1] = __uint_as_float((r) & 0xffff0000u);                   \
        p = __builtin_elementwise_fma(bcast_lo(e7), w[14], p);        \
        p = __builtin_elementwise_fma(bcast_hi(e7), w[15], p);        \
        float2v m = p + hv;                                           \
        acc += __builtin_elementwise_max(m, z2);                      \
    }

    if (i + 4 <= e1) {
        int svn = csrc[i + (lane >> 4)];
        do {
            int sv = svn;
            if (i + 8 <= e1) svn = csrc[i + 4 + (lane >> 4)];
            const int s0 = __builtin_amdgcn_readlane(sv, 0);
            const int s1 = __builtin_amdgcn_readlane(sv, 16);
            const int s2 = __builtin_amdgcn_readlane(sv, 32);
            const int s3 = __builtin_amdgcn_readlane(sv, 48);
            // issue all 4 gathers first (longest latency)
            unsigned r0 = *(const unsigned*)&hb[(size_t)s0 * D + ch0];
            unsigned r1 = *(const unsigned*)&hb[(size_t)s1 * D + ch0];
            unsigned r2 = *(const unsigned*)&hb[(size_t)s2 * D + ch0];
            unsigned r3 = *(const unsigned*)&hb[(size_t)s3 * D + ch0];
            const float2v* ep = (const float2v*)(eacsr + (size_t)i * 16);
            COMPE(ep, r0);
            COMPE(ep + 8, r1);
            COMPE(ep + 16, r2);
            COMPE(ep + 24, r3);
            i += 4;
        } while (i + 4 <= e1);
    }
    for (; i < e1; ++i) {  // tail (<=3 edges)
        const int se = __builtin_amdgcn_readfirstlane(csrc[i]);
        unsigned r = *(const unsigned*)&hb[(size_t)se * D + ch0];
        COMPE((const float2v*)(eacsr + (size_t)i * 16), r);
    }
#undef COMPE

    // epilogue: u = h_v + acc -> bf16 hi/lo
    float2v sv2 = *(const float2v*)&h[(size_t)v * D + ch0];
    float u0 = sv2[0] + acc[0];
    float u1 = sv2[1] + acc[1];
    ushort h0 = f2bf_rne(u0);
    ushort h1 = f2bf_rne(u1);
    ushort l0 = f2bf_rne(u0 - bf2f(h0));
    ushort l1 = f2bf_rne(u1 - bf2f(h1));
    *(ushort2*)&uhi[(size_t)v * D + ch0] = make_ushort2(h0, h1);
    *(ushort2*)&ulo[(size_t)v * D + ch0] = make_ushort2(l0, l1);
}

// ---------------- Split-bf16 MFMA GEMM (+ optional fused BN stats) ---------
template <int WRITE_BF16, int STATS>
__global__ __launch_bounds__(256) void gemm_mfma(
    const ushort* __restrict__ Ah, const ushort* __restrict__ Al,
    const ushort* __restrict__ Bh, const ushort* __restrict__ Bl,
    const float* __restrict__ bias,
    float* __restrict__ Cf, ushort* __restrict__ Chi, ushort* __restrict__ Clo,
    float* __restrict__ stats, int Nreal,
    int N, int K, int relu) {
    __shared__ ushort sA[2][128][72];
    __shared__ ushort sB[2][64][72];
    const int tid = threadIdx.x;
    const int wave = tid >> 6, lane = tid & 63;
    const int lrow = lane & 15, lquad = lane >> 4;
    const int bm = blockIdx.y * 128;
    const int bn = blockIdx.x * 64;

    floatx4 acc[2][4];
#pragma unroll
    for (int i = 0; i < 2; ++i)
#pragma unroll
        for (int j = 0; j < 4; ++j) acc[i][j] = (floatx4)0.f;

    for (int k0 = 0; k0 < K; k0 += 64) {
        for (int s = tid; s < 1024; s += 256) {
            int row = s >> 3, c8 = (s & 7) * 8;
            size_t g = (size_t)(bm + row) * K + k0 + c8;
            *(int4*)&sA[0][row][c8] = *(const int4*)&Ah[g];
            *(int4*)&sA[1][row][c8] = *(const int4*)&Al[g];
        }
        for (int s = tid; s < 512; s += 256) {
            int row = s >> 3, c8 = (s & 7) * 8;
            size_t g = (size_t)(bn + row) * K + k0 + c8;
            *(int4*)&sB[0][row][c8] = *(const int4*)&Bh[g];
            *(int4*)&sB[1][row][c8] = *(const int4*)&Bl[g];
        }
        __syncthreads();
        const int rb = wave * 32;
#pragma unroll
        for (int kk = 0; kk < 2; ++kk) {
            int ko = kk * 32 + lquad * 8;
            short8 ah[2], al[2], bh[4], bl[4];
#pragma unroll
            for (int i = 0; i < 2; ++i) {
                ah[i] = *(const short8*)&sA[0][rb + i * 16 + lrow][ko];
                al[i] = *(const short8*)&sA[1][rb + i * 16 + lrow][ko];
            }
#pragma unroll
            for (int j = 0; j < 4; ++j) {
                bh[j] = *(const short8*)&sB[0][j * 16 + lrow][ko];
                bl[j] = *(const short8*)&sB[1][j * 16 + lrow][ko];
            }
#pragma unroll
            for (int i = 0; i < 2; ++i)
#pragma unroll
                for (int j = 0; j < 4; ++j) {
                    acc[i][j] = __builtin_amdgcn_mfma_f32_16x16x32_bf16(
                        ah[i], bh[j], acc[i][j], 0, 0, 0);
                    acc[i][j] = __builtin_amdgcn_mfma_f32_16x16x32_bf16(
                        ah[i], bl[j], acc[i][j], 0, 0, 0);
                    acc[i][j] = __builtin_amdgcn_mfma_f32_16x16x32_bf16(
                        al[i], bh[j], acc[i][j], 0, 0, 0);
                }
        }
        __syncthreads();
    }
    float sj[4] = {0.f, 0.f, 0.f, 0.f};
    float qj[4] = {0.f, 0.f, 0.f, 0.f};
#pragma unroll
    for (int i = 0; i < 2; ++i)
#pragma unroll
        for (int j = 0; j < 4; ++j) {
            int gc = bn + j * 16 + lrow;
            float bv = bias[gc];
#pragma unroll
            for (int r = 0; r < 4; ++r) {
                int gr = bm + wave * 32 + i * 16 + lquad * 4 + r;
                float v = acc[i][j][r] + bv;
                if (relu) v = fmaxf(v, 0.f);
                if (STATS && gr < Nreal) {
                    sj[j] += v;
                    qj[j] = fmaf(v, v, qj[j]);
                }
                if (WRITE_BF16) {
                    ushort hv = f2bf_rne(v);
                    ushort lv = f2bf_rne(v - bf2f(hv));
                    Chi[(size_t)gr * N + gc] = hv;
                    Clo[(size_t)gr * N + gc] = lv;
                } else {
                    Cf[(size_t)gr * N + gc] = v;
                }
            }
        }
    if (STATS) {
#pragma unroll
        for (int j = 0; j < 4; ++j) {
            float s = sj[j], q = qj[j];
            s += __shfl_xor(s, 16);
            s += __shfl_xor(s, 32);
            q += __shfl_xor(q, 16);
            q += __shfl_xor(q, 32);
            if (lquad == 0) {
                int gc = bn + j * 16 + lrow;
                atomicAdd(&stats[gc], s);
                atomicAdd(&stats[N + gc], q);
            }
        }
    }
}

// ---------------- BatchNorm apply (vectorized, + bf16 copy) ----------------
__global__ __launch_bounds__(256) void bn_apply_kernel(
    const float* __restrict__ r, float* __restrict__ h,
    ushort* __restrict__ hbout,
    const float* __restrict__ sums,
    const float* __restrict__ g, const float* __restrict__ bt,
    int N, int D, int Dm1) {
    int idx = blockIdx.x * blockDim.x + threadIdx.x;
    int total4 = N * D / 4;
    int stride = gridDim.x * blockDim.x;
    float invN = 1.0f / (float)N;
    for (; idx < total4; idx += stride) {
        int c = (idx * 4) & Dm1;
        float4 s4 = *(const float4*)&sums[c];
        float4 q4 = *(const float4*)&sums[D + c];
        float4 g4 = *(const float4*)&g[c];
        float4 b4 = *(const float4*)&bt[c];
        float4 r4 = ((const float4*)r)[idx];
        float4 o;
        {
            float mu = s4.x * invN;
            float var = fmaf(-mu, mu, q4.x * invN);
            o.x = (r4.x - mu) * (rsqrtf(var + 1e-5f) * g4.x) + b4.x;
            mu = s4.y * invN;
            var = fmaf(-mu, mu, q4.y * invN);
            o.y = (r4.y - mu) * (rsqrtf(var + 1e-5f) * g4.y) + b4.y;
            mu = s4.z * invN;
            var = fmaf(-mu, mu, q4.z * invN);
            o.z = (r4.z - mu) * (rsqrtf(var + 1e-5f) * g4.z) + b4.z;
            mu = s4.w * invN;
            var = fmaf(-mu, mu, q4.w * invN);
            o.w = (r4.w - mu) * (rsqrtf(var + 1e-5f) * g4.w) + b4.w;
        }
        ((float4*)h)[idx] = o;
        if (hbout) {
            ushort4 ob;
            ob.x = f2bf_rne(o.x);
            ob.y = f2bf_rne(o.y);
            ob.z = f2bf_rne(o.z);
            ob.w = f2bf_rne(o.w);
            ((ushort4*)hbout)[idx] = ob;
        }
    }
}

// ---------------- Head ----------------
__global__ void head_kernel(const float* __restrict__ h, const int* __restrict__ n_nodes,
                            const float* __restrict__ Wf1, const float* __restrict__ bf1,
                            const float* __restrict__ Wf2, const float* __restrict__ bf2,
                            float* __restrict__ out, int G) {
    int g = blockIdx.x * blockDim.x + threadIdx.x;
    if (g >= G) return;
    int s = 0;
    for (int i = 0; i <= g; ++i) s += n_nodes[i];
    const float* m = &h[(size_t)(s - 1) * 64];
    float o = bf2[0];
#pragma unroll 4
    for (int j = 0; j < 16; ++j) {
        float acc = bf1[j];
        for (int k = 0; k < 64; ++k) acc = fmaf(m[k], Wf1[k * 16 + j], acc);
        acc = fmaxf(acc, 0.f);
        o = fmaf(acc, Wf2[j], o);
    }
    out[g] = o;
}

extern "C" void kernel_launch(void* const* d_in, const int* in_sizes, int n_in,
                              void* d_out, int out_size, void* d_ws, size_t ws_size,
                              hipStream_t stream) {
    const float* x = (const float*)d_in[0];
    const float* ea = (const float*)d_in[1];
    const int* eidx = (const int*)d_in[2];
    const int* n_nodes = (const int*)d_in[3];
    const float* We1 = (const float*)d_in[4];
    const float* be1 = (const float*)d_in[5];
    const float* W11 = (const float*)d_in[6];
    const float* b11 = (const float*)d_in[7];
    const float* W12 = (const float*)d_in[8];
    const float* b12 = (const float*)d_in[9];
    const float* g1 = (const float*)d_in[10];
    const float* bt1 = (const float*)d_in[11];
    const float* We2 = (const float*)d_in[12];
    const float* be2 = (const float*)d_in[13];
    const float* W21 = (const float*)d_in[14];
    const float* b21 = (const float*)d_in[15];
    const float* W22 = (const float*)d_in[16];
    const float* b22 = (const float*)d_in[17];
    const float* g2 = (const float*)d_in[18];
    const float* bt2 = (const float*)d_in[19];
    const float* We3 = (const float*)d_in[20];
    const float* be3 = (const float*)d_in[21];
    const float* W31 = (const float*)d_in[22];
    const float* b31 = (const float*)d_in[23];
    const float* W32 = (const float*)d_in[24];
    const float* b32 = (const float*)d_in[25];
    const float* g3 = (const float*)d_in[26];
    const float* bt3 = (const float*)d_in[27];
    const float* Wf1 = (const float*)d_in[28];
    const float* bf1 = (const float*)d_in[29];
    const float* Wf2 = (const float*)d_in[30];
    const float* bf2 = (const float*)d_in[31];

    const int N = in_sizes[0] / 128;  // 50000
    const int E = in_sizes[2] / 2;    // 800000
    const int G = in_sizes[3];        // 500
    const int Mp = ((N + 127) / 128) * 128;  // 50048
    const int* srcp = eidx;
    const int* dstp = eidx + E;

    float* H = (float*)d_ws;            // Mp x 256 fp32
    float* UR = H + (size_t)Mp * 256;   // Mp x 256: u(hi/lo bf16) / r(fp32)
    float* TT = UR + (size_t)Mp * 256;  // Mp x 256: t(hi/lo bf16) / hb(bf16)
    float* stats1 = TT + (size_t)Mp * 256;  // 512
    float* stats2 = stats1 + 512;           // 256
    float* stats3 = stats2 + 256;           // 128
    int* deg = (int*)(stats3 + 128);        // N
    int* cursor = deg + N;                  // N
    int* row_start = cursor + N;            // N+1 (+1 pad)
    int* ceid = row_start + N + 2;          // E
    int* csrc = ceid + E;                   // E (+2 pad)
    ushort* wp = (ushort*)(csrc + E + 2);
    ushort* W11th = wp; wp += 128 * 256;
    ushort* W11tl = wp; wp += 128 * 256;
    ushort* W12th = wp; wp += 256 * 256;
    ushort* W12tl = wp; wp += 256 * 256;
    ushort* W21th = wp; wp += 256 * 128;
    ushort* W21tl = wp; wp += 256 * 128;
    ushort* W22th = wp; wp += 128 * 128;
    ushort* W22tl = wp; wp += 128 * 128;
    ushort* W31th = wp; wp += 128 * 64;
    ushort* W31tl = wp; wp += 128 * 64;
    ushort* W32th = wp; wp += 64 * 64;
    ushort* W32tl = wp; wp += 64 * 64;
    // align to 16B for eacsr
    float* eacsr;
    {
        size_t off = (size_t)((char*)wp - (char*)d_ws);
        off = (off + 15) & ~(size_t)15;
        eacsr = (float*)((char*)d_ws + off);  // E x 16 fp32 = 51.2 MB
    }

    hipMemsetAsync(stats1, 0, 896 * sizeof(float) + (size_t)2 * N * sizeof(int), stream);

    const int prepTot = 128 * 256 + 256 * 256 + 256 * 128 + 128 * 128 + 128 * 64 + 64 * 64;
    prep_all<<<(prepTot + 255) / 256, 256, 0, stream>>>(
        W11, W11th, W11tl, W12, W12th, W12tl, W21, W21th, W21tl,
        W22, W22th, W22tl, W31, W31th, W31tl, W32, W32th, W32tl);

    hist_kernel<<<3125, 256, 0, stream>>>(dstp, deg, E);
    scan_kernel<<<1, 1024, 0, stream>>>(deg, row_start, N);
    scatter_kernel<<<3125, 256, 0, stream>>>(srcp, dstp, row_start, cursor, ceid, csrc, E);
    eacsr_gather<<<12500, 256, 0, stream>>>(ea, ceid, eacsr, (long)E * 16);

    const int gy = Mp / 128;
    float* R = UR;
    ushort* HB = (ushort*)TT;  // bf16 gather copy lives in the (dead) TT region

    // ---------------- Layer 1: 128 -> 256 -> 256 ----------------
    {
        ushort* Uhi = (ushort*)UR; ushort* Ulo = Uhi + (size_t)Mp * 128;
        ushort* Thi = (ushort*)TT; ushort* Tlo = Thi + (size_t)Mp * 256;
        f32_to_bf16<<<2048, 256, 0, stream>>>(x, HB, (long)N * 128 / 4);
        gine_agg_kernel<128, 1><<<(N + 3) / 4, 256, 0, stream>>>(
            x, HB, eacsr, row_start, csrc, We1, be1, Uhi, Ulo, N);
        gemm_mfma<1, 0><<<dim3(4, gy), 256, 0, stream>>>(
            Uhi, Ulo, W11th, W11tl, b11, nullptr, Thi, Tlo, nullptr, 0, 256, 128, 1);
        gemm_mfma<0, 1><<<dim3(4, gy), 256, 0, stream>>>(
            Thi, Tlo, W12th, W12tl, b12, R, nullptr, nullptr, stats1, N, 256, 256, 1);
        bn_apply_kernel<<<2048, 256, 0, stream>>>(R, H, HB, stats1, g1, bt1, N, 256, 255);
    }

    // ---------------- Layer 2: 256 -> 128 -> 128 ----------------
    {
        ushort* Uhi = (ushort*)UR; ushort* Ulo = Uhi + (size_t)Mp * 256;
        ushort* Thi = (ushort*)TT; ushort* Tlo = Thi + (size_t)Mp * 128;
        gine_agg_kernel<256, 2><<<(N + 1) / 2, 256, 0, stream>>>(
            H, HB, eacsr, row_start, csrc, We2, be2, Uhi, Ulo, N);
        gemm_mfma<1, 0><<<dim3(2, gy), 256, 0, stream>>>(
            Uhi, Ulo, W21th, W21tl, b21, nullptr, Thi, Tlo, nullptr, 0, 128, 256, 1);
        gemm_mfma<0, 1><<<dim3(2, gy), 256, 0, stream>>>(
            Thi, Tlo, W22th, W22tl, b22, R, nullptr, nullptr, stats2, N, 128, 128, 1);
        bn_apply_kernel<<<2048, 256, 0, stream>>>(R, H, HB, stats2, g2, bt2, N, 128, 127);
    }

    // ---------------- Layer 3: 128 -> 64 -> 64 ----------------
    {
        ushort* Uhi = (ushort*)UR; ushort* Ulo = Uhi + (size_t)Mp * 128;
        ushort* Thi = (ushort*)TT; ushort* Tlo = Thi + (size_t)Mp * 64;
        gine_agg_kernel<128, 1><<<(N + 3) / 4, 256, 0, stream>>>(
            H, HB, eacsr, row_start, csrc, We3, be3, Uhi, Ulo, N);
        gemm_mfma<1, 0><<<dim3(1, gy), 256, 0, stream>>>(
            Uhi, Ulo, W31th, W31tl, b31, nullptr, Thi, Tlo, nullptr, 0, 64, 128, 1);
        gemm_mfma<0, 1><<<dim3(1, gy), 256, 0, stream>>>(
            Thi, Tlo, W32th, W32tl, b32, R, nullptr, nullptr, stats3, N, 64, 64, 1);
        bn_apply_kernel<<<2048, 256, 0, stream>>>(R, H, nullptr, stats3, g3, bt3, N, 64, 63);
    }

    // ---------------- Head ----------------
    head_kernel<<<(G + 255) / 256, 256, 0, stream>>>(H, n_nodes, Wf1, bf1, Wf2, bf2,
                                                     (float*)d_out, G);
}